// Round 6
// baseline (333.121 us; speedup 1.0000x reference)
//
#include <hip/hip_runtime.h>

// Segment-mean of subtoken embeddings (sorted segment ids) -> token embeddings.
//
// ROUND 6 = DIAGNOSTIC ROUND. Production pipeline (table_kernel +
// seg_mean_kernel) is unchanged from round 5 (passed, absmax 0, ~63us).
// Rounds 1-5 all plateau at ~2 TB/s regardless of structure while the
// harness's 400 MB fillBuffer hits 6.6 TB/s. Two probes run AFTER the
// production kernels to measure this container's achievable BW for
// (a) read-dominated streaming and (b) read+write copy, in the exact same
// memory environment. They only touch d_ws beyond the table region.

typedef float v4f __attribute__((ext_vector_type(4)));

#define TPW 4          // tokens per wave
#define WPB 4          // waves per block (256 threads)
#define TPB (TPW * WPB)
#define RCHUNK 4       // rows preloaded per inner iteration

__global__ void table_kernel(const int* __restrict__ seg,
                             const int* __restrict__ num_tokens_p,
                             int* __restrict__ table,
                             int BS_total,   // B*S
                             int BT) {       // B*T
  const int T = num_tokens_p[0];
  const int B = BT / T;
  const int S = BS_total / B;
  int s = blockIdx.x * blockDim.x + threadIdx.x;
  if (s >= BS_total) return;
  const int b = s / S;
  const int cur = b * T + seg[s];
  const int prev = (s == 0) ? -1 : ((s - 1) / S) * T + seg[s - 1];
  for (int g = prev + 1; g <= cur; ++g) table[g] = s;
  if (s == BS_total - 1) {
    for (int g = cur + 1; g <= BT; ++g) table[g] = BS_total;
  }
}

template <int NCH>
__global__ __launch_bounds__(WPB * 64) void seg_mean_kernel(
    const float* __restrict__ hs,      // [B*S, D] flat
    const int* __restrict__ table,     // [BT+1]
    float* __restrict__ out,           // [BT, D] flat
    int BT,
    int D4) {                          // D/4 (= NCH*64)
  const int lane = threadIdx.x & 63;
  const int wid = threadIdx.x >> 6;
  const int g0 = (blockIdx.x * WPB + wid) * TPW;
  if (g0 >= BT) return;
  const int ntok = min(TPW, BT - g0);

  int bnd[TPW + 1];
#pragma unroll
  for (int i = 0; i <= TPW; ++i)
    bnd[i] = table[g0 + ((i <= ntok) ? i : ntok)];  // pad -> empty tokens

  const v4f* __restrict__ hs4 = (const v4f*)hs;
  v4f* __restrict__ out4 = (v4f*)out;

  int r = bnd[0];
  const int rend = bnd[TPW];
  int tok = 0;

  v4f acc[NCH];
#pragma unroll
  for (int c = 0; c < NCH; ++c) acc[c] = (v4f)(0.f);

#define FLUSH_AT(R)                                                          \
  while (tok < TPW && bnd[tok + 1] <= (R)) {                                 \
    const int cnt = bnd[tok + 1] - bnd[tok];                                 \
    const float inv = (cnt > 0) ? (1.0f / (float)cnt) : 0.0f;                \
    if (tok < ntok) {                                                        \
      v4f* __restrict__ q = out4 + (size_t)(g0 + tok) * D4 + lane;           \
      _Pragma("unroll")                                                      \
      for (int c = 0; c < NCH; ++c) {                                        \
        v4f o = acc[c] * inv;                                                \
        __builtin_nontemporal_store(o, q + c * 64);                          \
      }                                                                      \
    }                                                                        \
    _Pragma("unroll")                                                        \
    for (int c = 0; c < NCH; ++c) acc[c] = (v4f)(0.f);                       \
    ++tok;                                                                   \
  }

  FLUSH_AT(r);  // leading empty tokens

  while (r < rend) {
    const int m = min(RCHUNK, rend - r);
    v4f v[RCHUNK][NCH];
#pragma unroll
    for (int j = 0; j < RCHUNK; ++j) {
      if (j < m) {
        const v4f* __restrict__ p = hs4 + (size_t)(r + j) * D4 + lane;
#pragma unroll
        for (int c = 0; c < NCH; ++c) v[j][c] = p[c * 64];
      }
    }
#pragma unroll
    for (int j = 0; j < RCHUNK; ++j) {
      if (j < m) {
#pragma unroll
        for (int c = 0; c < NCH; ++c) acc[c] += v[j][c];
        FLUSH_AT(r + j + 1);
      }
    }
    r += m;
  }

  FLUSH_AT(rend);
  while (tok < TPW) {
    if (tok < ntok) {
      v4f* __restrict__ q = out4 + (size_t)(g0 + tok) * D4 + lane;
      const v4f z = (v4f)(0.f);
#pragma unroll
      for (int c = 0; c < NCH; ++c) __builtin_nontemporal_store(z, q + c * 64);
    }
    ++tok;
  }
#undef FLUSH_AT
}

__global__ void seg_mean_fallback(const float* __restrict__ hs,
                                  const int* __restrict__ table,
                                  float* __restrict__ out,
                                  int D) {
  const int g = blockIdx.x;
  const int lo = table[g];
  const int hi = table[g + 1];
  const int cnt = hi - lo;
  const float inv = (cnt > 0) ? (1.0f / (float)cnt) : 0.0f;
  for (int d = threadIdx.x; d < D; d += blockDim.x) {
    float a = 0.f;
    for (int r = lo; r < hi; ++r) a += hs[(size_t)r * D + d];
    out[(size_t)g * D + d] = a * inv;
  }
}

// ---------------- diagnostics (touch only d_ws) ----------------

// Read-dominated: 2 grid-stride passes over n4 float4s, accumulate, one
// small store per thread. Measures achievable streaming READ BW.
__global__ void probe_read(const v4f* __restrict__ src, size_t n4,
                           v4f* __restrict__ sink) {
  const size_t tid = (size_t)blockIdx.x * blockDim.x + threadIdx.x;
  const size_t stride = (size_t)gridDim.x * blockDim.x;
  v4f acc = (v4f)(0.f);
  for (int pass = 0; pass < 2; ++pass) {
    for (size_t i = tid; i < n4; i += stride) acc += src[i];
  }
  sink[tid] = acc;
}

// Copy: 2 passes src -> dst. Measures achievable READ+WRITE BW.
__global__ void probe_copy(const v4f* __restrict__ src, v4f* __restrict__ dst,
                           size_t n4) {
  const size_t tid = (size_t)blockIdx.x * blockDim.x + threadIdx.x;
  const size_t stride = (size_t)gridDim.x * blockDim.x;
  for (int pass = 0; pass < 2; ++pass) {
    for (size_t i = tid; i < n4; i += stride) dst[i] = src[i];
  }
}

extern "C" void kernel_launch(void* const* d_in, const int* in_sizes, int n_in,
                              void* d_out, int out_size, void* d_ws, size_t ws_size,
                              hipStream_t stream) {
  const float* hs = (const float*)d_in[0];
  const int* seg = (const int*)d_in[1];
  const int* num_tokens_p = (const int*)d_in[2];
  float* out = (float*)d_out;

  const int BS_total = in_sizes[1];            // B*S
  const int D = in_sizes[0] / in_sizes[1];     // 768
  const int BT = out_size / D;                 // B*T

  int* table = (int*)d_ws;                     // BT+1 ints at ws offset 0

  const int threads1 = 256;
  const int grid1 = (BS_total + threads1 - 1) / threads1;
  hipLaunchKernelGGL(table_kernel, dim3(grid1), dim3(threads1), 0, stream,
                     seg, num_tokens_p, table, BS_total, BT);

  const int D4 = D / 4;
  const int grid2 = (BT + TPB - 1) / TPB;
  if (D % 4 == 0 && D4 % 64 == 0 && D4 / 64 >= 1 && D4 / 64 <= 4) {
    switch (D4 / 64) {
      case 1:
        hipLaunchKernelGGL(seg_mean_kernel<1>, dim3(grid2), dim3(WPB * 64), 0,
                           stream, hs, table, out, BT, D4);
        break;
      case 2:
        hipLaunchKernelGGL(seg_mean_kernel<2>, dim3(grid2), dim3(WPB * 64), 0,
                           stream, hs, table, out, BT, D4);
        break;
      case 3:
        hipLaunchKernelGGL(seg_mean_kernel<3>, dim3(grid2), dim3(WPB * 64), 0,
                           stream, hs, table, out, BT, D4);
        break;
      default:
        hipLaunchKernelGGL(seg_mean_kernel<4>, dim3(grid2), dim3(WPB * 64), 0,
                           stream, hs, table, out, BT, D4);
        break;
    }
  } else {
    hipLaunchKernelGGL(seg_mean_fallback, dim3(BT), dim3(256), 0, stream,
                       hs, table, out, D);
  }

  // ---- diagnostics AFTER production kernels (identical env for seg_mean) --
  // ws layout: [0,1MB) table, [1MB,9MB) probe sink, [16MB,216MB) read region,
  // [216MB,316MB) copy dst. Only run if ws is big enough.
  const size_t MB = 1024 * 1024;
  char* wsb = (char*)d_ws;
  const size_t hs_bytes = (size_t)in_sizes[0] * 4;
  if (ws_size >= 316 * MB) {
    // probe 1: read 2 x 200 MB of ws (poisoned 0xAA -> tiny denormal floats)
    const size_t n4r = (200 * MB) / 16;
    hipLaunchKernelGGL(probe_read, dim3(2048), dim3(256), 0, stream,
                       (const v4f*)(wsb + 16 * MB), n4r,
                       (v4f*)(wsb + 1 * MB));
    // probe 2: copy hs (100 MB) -> ws, twice
    const size_t n4c = hs_bytes / 16;
    hipLaunchKernelGGL(probe_copy, dim3(2048), dim3(256), 0, stream,
                       (const v4f*)hs, (v4f*)(wsb + 216 * MB), n4c);
  }
}